// Round 1
// baseline (23403.021 us; speedup 1.0000x reference)
//
#include <hip/hip_runtime.h>

#define T_STEPS 8192
#define NRES    2048
#define DIN     64
#define DOUT    64

typedef unsigned long long u64;
typedef unsigned int u32;

// ---------------------------------------------------------------------------
// ws layout:
//   [0, 64MB)          : states fp32 [T][NRES]
//   [64MB, +48KB)      : ring    u64 [3][NRES]   (tagged words {val<<32 | tag})
//   [64MB+48KB, +512KB): WT      fp32 [NRES][DOUT] (W_out transposed)
// ---------------------------------------------------------------------------

__global__ __launch_bounds__(256) void esn_init_ring(u64* __restrict__ ring) {
  int idx = blockIdx.x * 256 + threadIdx.x;
  if (idx < 3 * NRES) ring[idx] = 0ull;
}

__global__ __launch_bounds__(256) void esn_transpose(const float* __restrict__ Wout,
                                                     float* __restrict__ WT) {
  int idx = blockIdx.x * 256 + threadIdx.x;  // 0 .. DOUT*NRES-1
  int d = idx >> 11;                         // / NRES
  int k = idx & (NRES - 1);
  WT[k * DOUT + d] = Wout[idx];
}

// Persistent scan: 256 blocks x 256 threads (1 block/CU, 4 waves/block).
// Block b owns rows [8b, 8b+8); wave w owns rows 8b+2w, 8b+2w+1.
// Lane l holds W[r][g*256 + 4l + j] for g=0..7, j=0..3  (64 regs).
// Communication: ring word j carries x[j] as {bits<<32 | (t+1)} via
// agent-scope relaxed atomics (performed at LLC -> cross-XCD safe, no fences).
__global__ __launch_bounds__(256) void esn_scan(const float* __restrict__ u,
                                                const float* __restrict__ Win,
                                                const float* __restrict__ W,
                                                float* __restrict__ states,
                                                u64* __restrict__ ring) {
  const int tid  = threadIdx.x;
  const int lane = tid & 63;
  const int wv   = tid >> 6;
  const int blk  = blockIdx.x;
  const int r0   = blk * 8 + wv * 2;
  const int r1   = r0 + 1;

  __shared__ float xs[NRES];

  // Load this wave's two W rows into registers (one-time, coalesced float4).
  float w0[32], w1[32];
#pragma unroll
  for (int g = 0; g < 8; ++g) {
    const float4 a = *(const float4*)(W + (size_t)r0 * NRES + g * 256 + lane * 4);
    w0[g * 4 + 0] = a.x; w0[g * 4 + 1] = a.y; w0[g * 4 + 2] = a.z; w0[g * 4 + 3] = a.w;
    const float4 c = *(const float4*)(W + (size_t)r1 * NRES + g * 256 + lane * 4);
    w1[g * 4 + 0] = c.x; w1[g * 4 + 1] = c.y; w1[g * 4 + 2] = c.z; w1[g * 4 + 3] = c.w;
  }
  const float win0 = Win[r0 * DIN + lane];
  const float win1 = Win[r1 * DIN + lane];

  for (int t = 0; t < T_STEPS; ++t) {
    __syncthreads();  // protect xs against writers while prior step still reads
    if (t == 0) {
#pragma unroll
      for (int j = 0; j < 8; ++j) xs[j * 256 + tid] = 0.0f;
    } else {
      const u64* rb  = ring + ((t + 2) % 3) * NRES;  // slot (t-1)%3
      const u32 want = (u32)t;                       // tag written at step t-1
      u64 v[8];
#pragma unroll
      for (int j = 0; j < 8; ++j)
        v[j] = __hip_atomic_load(rb + j * 256 + tid, __ATOMIC_RELAXED,
                                 __HIP_MEMORY_SCOPE_AGENT);
      for (;;) {
        bool ok = true;
#pragma unroll
        for (int j = 0; j < 8; ++j) ok = ok && ((u32)v[j] == want);
        if (ok) break;
#pragma unroll
        for (int j = 0; j < 8; ++j)
          if ((u32)v[j] != want)
            v[j] = __hip_atomic_load(rb + j * 256 + tid, __ATOMIC_RELAXED,
                                     __HIP_MEMORY_SCOPE_AGENT);
      }
#pragma unroll
      for (int j = 0; j < 8; ++j)
        xs[j * 256 + tid] = __uint_as_float((u32)(v[j] >> 32));
    }
    __syncthreads();

    // acc = W_in[r,:] . u_t  +  W[r,:] . x_{t-1}   (per-lane partial)
    const float uv = u[t * DIN + lane];
    float a0 = win0 * uv;
    float a1 = win1 * uv;
#pragma unroll
    for (int g = 0; g < 8; ++g) {
      const float4 xv = *(const float4*)(xs + g * 256 + lane * 4);
      a0 = fmaf(w0[g * 4 + 0], xv.x, a0);
      a0 = fmaf(w0[g * 4 + 1], xv.y, a0);
      a0 = fmaf(w0[g * 4 + 2], xv.z, a0);
      a0 = fmaf(w0[g * 4 + 3], xv.w, a0);
      a1 = fmaf(w1[g * 4 + 0], xv.x, a1);
      a1 = fmaf(w1[g * 4 + 1], xv.y, a1);
      a1 = fmaf(w1[g * 4 + 2], xv.z, a1);
      a1 = fmaf(w1[g * 4 + 3], xv.w, a1);
    }
    // 64-lane butterfly all-reduce
#pragma unroll
    for (int off = 32; off > 0; off >>= 1) {
      a0 += __shfl_xor(a0, off, 64);
      a1 += __shfl_xor(a1, off, 64);
    }
    if (lane < 2) {
      const float s  = (lane == 0) ? a0 : a1;
      const float xv = tanhf(s);
      const int r    = r0 + lane;
      states[(size_t)t * NRES + r] = xv;  // plain store; flushed at kernel end
      const u64 word = ((u64)__float_as_uint(xv) << 32) | (u32)(t + 1);
      __hip_atomic_store(ring + (t % 3) * NRES + r, word, __ATOMIC_RELAXED,
                         __HIP_MEMORY_SCOPE_AGENT);
    }
  }
}

// Y = states @ W_out^T + b : block = 16 timesteps, wave-group of 64 lanes
// handles 4 timesteps; lane = output dim (coalesced WT reads, uniform states
// reads -> scalar path).
__global__ __launch_bounds__(256) void esn_out_gemm(const float* __restrict__ states,
                                                    const float* __restrict__ WT,
                                                    const float* __restrict__ bout,
                                                    float* __restrict__ out) {
  const int tid  = threadIdx.x;
  const int lane = tid & 63;
  const int grp  = tid >> 6;
  const int t0   = blockIdx.x * 16 + grp * 4;

  float acc0 = 0.f, acc1 = 0.f, acc2 = 0.f, acc3 = 0.f;
  const float* s0 = states + (size_t)(t0 + 0) * NRES;
  const float* s1 = states + (size_t)(t0 + 1) * NRES;
  const float* s2 = states + (size_t)(t0 + 2) * NRES;
  const float* s3 = states + (size_t)(t0 + 3) * NRES;

  for (int k = 0; k < NRES; k += 4) {
    const float4 a = *(const float4*)(s0 + k);
    const float4 b = *(const float4*)(s1 + k);
    const float4 c = *(const float4*)(s2 + k);
    const float4 d = *(const float4*)(s3 + k);
    const float wA = WT[(k + 0) * DOUT + lane];
    const float wB = WT[(k + 1) * DOUT + lane];
    const float wC = WT[(k + 2) * DOUT + lane];
    const float wD = WT[(k + 3) * DOUT + lane];
    acc0 = fmaf(a.x, wA, acc0); acc0 = fmaf(a.y, wB, acc0);
    acc0 = fmaf(a.z, wC, acc0); acc0 = fmaf(a.w, wD, acc0);
    acc1 = fmaf(b.x, wA, acc1); acc1 = fmaf(b.y, wB, acc1);
    acc1 = fmaf(b.z, wC, acc1); acc1 = fmaf(b.w, wD, acc1);
    acc2 = fmaf(c.x, wA, acc2); acc2 = fmaf(c.y, wB, acc2);
    acc2 = fmaf(c.z, wC, acc2); acc2 = fmaf(c.w, wD, acc2);
    acc3 = fmaf(d.x, wA, acc3); acc3 = fmaf(d.y, wB, acc3);
    acc3 = fmaf(d.z, wC, acc3); acc3 = fmaf(d.w, wD, acc3);
  }
  const float bb = bout[lane];
  out[(size_t)(t0 + 0) * DOUT + lane] = acc0 + bb;
  out[(size_t)(t0 + 1) * DOUT + lane] = acc1 + bb;
  out[(size_t)(t0 + 2) * DOUT + lane] = acc2 + bb;
  out[(size_t)(t0 + 3) * DOUT + lane] = acc3 + bb;
}

extern "C" void kernel_launch(void* const* d_in, const int* in_sizes, int n_in,
                              void* d_out, int out_size, void* d_ws, size_t ws_size,
                              hipStream_t stream) {
  const float* u    = (const float*)d_in[0];
  const float* Win  = (const float*)d_in[1];
  const float* W    = (const float*)d_in[2];
  const float* Wout = (const float*)d_in[3];
  const float* bout = (const float*)d_in[4];
  float* out = (float*)d_out;

  char* ws = (char*)d_ws;
  float* states = (float*)ws;
  u64*   ring   = (u64*)(ws + (size_t)T_STEPS * NRES * sizeof(float));
  float* WT     = (float*)(ws + (size_t)T_STEPS * NRES * sizeof(float)
                              + (size_t)3 * NRES * sizeof(u64));

  hipLaunchKernelGGL(esn_init_ring, dim3(24), dim3(256), 0, stream, ring);
  hipLaunchKernelGGL(esn_transpose, dim3((DOUT * NRES) / 256), dim3(256), 0, stream,
                     Wout, WT);
  hipLaunchKernelGGL(esn_scan, dim3(256), dim3(256), 0, stream,
                     u, Win, W, states, ring);
  hipLaunchKernelGGL(esn_out_gemm, dim3(T_STEPS / 16), dim3(256), 0, stream,
                     states, WT, bout, out);
}